// Round 1
// baseline (284.138 us; speedup 1.0000x reference)
//
#include <hip/hip_runtime.h>

#define H     128
#define NP    512
#define NVOX  50000
#define NEDGE 800000
#define EPV   16        // edges per voxel = NEDGE/NVOX
#define SLOPE 0.01f
#define GR    32        // rows per block in k_gemm

// tanh(x) = 1 - 2/(exp(2x)+1); robust at +/-inf, ~2-3 ulp
__device__ __forceinline__ float fast_tanh(float xx) {
    float e = __expf(2.f * xx);
    return 1.f - 2.f * __builtin_amdgcn_rcpf(e + 1.f);
}

// ---------------- xp = x @ W_program + b_program  (512 x 128) ----------------
__global__ __launch_bounds__(128) void k_xp(const float* __restrict__ x,
                                            const float* __restrict__ Wp,
                                            const float* __restrict__ bp,
                                            float* __restrict__ xpout) {
    __shared__ float xr[H];
    int row = blockIdx.x, j = threadIdx.x;
    xr[j] = x[row * H + j];
    __syncthreads();
    float acc = bp[j];
#pragma unroll 8
    for (int k = 0; k < H; ++k) acc = fmaf(xr[k], Wp[k * H + j], acc);
    xpout[row * H + j] = acc;
}

// ------- vv = v @ W_voxel + b_voxel ; mask = sigmoid(lrelu(v@Wm1+bm1)@Wm2+bm2) -------
__global__ __launch_bounds__(256) void k_gemm(const float* __restrict__ v,
                                              const float* __restrict__ Wv,
                                              const float* __restrict__ bv,
                                              const float* __restrict__ Wm1,
                                              const float* __restrict__ bm1,
                                              const float* __restrict__ Wm2,
                                              const float* __restrict__ bm2,
                                              float* __restrict__ vv,
                                              float* __restrict__ mask_out) {
    __shared__ float vt[GR][H];   // 16 KB
    int tid  = threadIdx.x;
    int base = blockIdx.x * GR;
    // stage v tile (guarded)
#pragma unroll
    for (int i = 0; i < (GR * H) / 256; ++i) {
        int f = i * 256 + tid;
        int r = f >> 7, c = f & 127;
        int gr = base + r;
        vt[r][c] = (gr < NVOX) ? v[(size_t)gr * H + c] : 0.f;
    }
    __syncthreads();

    int tj = tid & 31;   // col group: cols 4*tj..4*tj+3
    int tr = tid >> 5;   // row group: rows 4*tr..4*tr+3
    int colbase = tj * 4;

    float aV[4][4], aM[4][4];
#pragma unroll
    for (int r = 0; r < 4; ++r)
#pragma unroll
        for (int c = 0; c < 4; ++c) { aV[r][c] = 0.f; aM[r][c] = 0.f; }

    for (int kq = 0; kq < H / 4; ++kq) {
        float sv[4][4];
#pragma unroll
        for (int r = 0; r < 4; ++r) {
            float4 t4 = *(const float4*)&vt[tr * 4 + r][kq * 4];
            sv[r][0] = t4.x; sv[r][1] = t4.y; sv[r][2] = t4.z; sv[r][3] = t4.w;
        }
#pragma unroll
        for (int kk = 0; kk < 4; ++kk) {
            int k = kq * 4 + kk;
            float4 wv = *(const float4*)&Wv[(size_t)k * H + colbase];
            float4 wm = *(const float4*)&Wm1[(size_t)k * H + colbase];
#pragma unroll
            for (int r = 0; r < 4; ++r) {
                float s = sv[r][kk];
                aV[r][0] = fmaf(s, wv.x, aV[r][0]);
                aV[r][1] = fmaf(s, wv.y, aV[r][1]);
                aV[r][2] = fmaf(s, wv.z, aV[r][2]);
                aV[r][3] = fmaf(s, wv.w, aV[r][3]);
                aM[r][0] = fmaf(s, wm.x, aM[r][0]);
                aM[r][1] = fmaf(s, wm.y, aM[r][1]);
                aM[r][2] = fmaf(s, wm.z, aM[r][2]);
                aM[r][3] = fmaf(s, wm.w, aM[r][3]);
            }
        }
    }

    float4 bv4  = *(const float4*)&bv[colbase];
    float4 bm14 = *(const float4*)&bm1[colbase];
    float4 wm24 = *(const float4*)&Wm2[colbase];
    float pm[4];
#pragma unroll
    for (int r = 0; r < 4; ++r) {
        int gr = base + tr * 4 + r;
        float o0 = aV[r][0] + bv4.x, o1 = aV[r][1] + bv4.y;
        float o2 = aV[r][2] + bv4.z, o3 = aV[r][3] + bv4.w;
        if (gr < NVOX) {
            *(float4*)&vv[(size_t)gr * H + colbase] = make_float4(o0, o1, o2, o3);
        }
        float m0 = aM[r][0] + bm14.x; m0 = (m0 >= 0.f) ? m0 : SLOPE * m0;
        float m1 = aM[r][1] + bm14.y; m1 = (m1 >= 0.f) ? m1 : SLOPE * m1;
        float m2 = aM[r][2] + bm14.z; m2 = (m2 >= 0.f) ? m2 : SLOPE * m2;
        float m3 = aM[r][3] + bm14.w; m3 = (m3 >= 0.f) ? m3 : SLOPE * m3;
        pm[r] = m0 * wm24.x + m1 * wm24.y + m2 * wm24.z + m3 * wm24.w;
    }
    // reduce over the 32 col-group lanes (aligned 32-lane groups within a wave)
#pragma unroll
    for (int off = 16; off >= 1; off >>= 1) {
#pragma unroll
        for (int r = 0; r < 4; ++r) pm[r] += __shfl_xor(pm[r], off, 64);
    }
    if (tj == 0) {
#pragma unroll
        for (int r = 0; r < 4; ++r) {
            int gr = base + tr * 4 + r;
            if (gr < NVOX) {
                float s = pm[r] + bm2[0];
                mask_out[gr] = __builtin_amdgcn_rcpf(1.f + __expf(-s));
            }
        }
    }
}

// ---- per-edge logits -> p = exp(e + gumbel); per-voxel partial sums of p ----
// one block per voxel; 16 lanes per edge, 4 edges per wave, 4 waves
__global__ __launch_bounds__(256) void k_edge(const float* __restrict__ xp,
                                              const float* __restrict__ vv,
                                              const int* __restrict__ cei,
                                              const float* __restrict__ theta,
                                              const float* __restrict__ gum,
                                              float* __restrict__ pout,
                                              float* __restrict__ partial) {
    __shared__ float ps[EPV];
    int j   = blockIdx.x;
    int tid = threadIdx.x;
    int lane_k = tid & 15;
    int t      = tid >> 4;          // 0..15
    int e      = j + t * NVOX;
    int src = cei[e];
    int dst = cei[NEDGE + e];
    const float4* xr = (const float4*)(xp + (size_t)src * H);
    const float4* vr = (const float4*)(vv + (size_t)dst * H);
    const float4* th = (const float4*)theta;
    float acc = 0.f;
#pragma unroll
    for (int i = 0; i < 2; ++i) {
        int q = lane_k + i * 16;                  // contiguous 256B across 16 lanes
        float4 a = xr[q], b = vr[q], c = th[q];
        acc += fast_tanh(a.x + b.x) * c.x;
        acc += fast_tanh(a.y + b.y) * c.y;
        acc += fast_tanh(a.z + b.z) * c.z;
        acc += fast_tanh(a.w + b.w) * c.w;
    }
#pragma unroll
    for (int off = 8; off >= 1; off >>= 1) acc += __shfl_xor(acc, off, 64);
    if (lane_k == 0) {
        float u = gum[e];
        float g = -__logf(-__logf(u));
        float p = __expf(acc + g);                // TAU = 1; no max-subtract (z <= ~26)
        pout[e] = p;
        ps[t]   = p;
    }
    __syncthreads();
    if (tid == 0) {
        float s = 0.f;
#pragma unroll
        for (int q = 0; q < EPV; ++q) s += ps[q];
        partial[j] = s;
    }
}

// ---------------- sum partials -> invS ----------------
__global__ __launch_bounds__(1024) void k_reduce(const float* __restrict__ partial,
                                                 float* __restrict__ invS) {
    __shared__ float wsum[16];
    int tid = threadIdx.x;
    float s = 0.f;
    for (int i = tid; i < NVOX; i += 1024) s += partial[i];
#pragma unroll
    for (int off = 32; off >= 1; off >>= 1) s += __shfl_xor(s, off, 64);
    if ((tid & 63) == 0) wsum[tid >> 6] = s;
    __syncthreads();
    if (tid == 0) {
        float tot = 0.f;
#pragma unroll
        for (int w = 0; w < 16; ++w) tot += wsum[w];
        invS[0] = 1.f / tot;
    }
}

// ---- y = p*invS, per-voxel argmax -> y_hard, summed = sum y*x[src], v_out ----
// 2 voxels per block, 128 threads (= cols) per voxel
__global__ __launch_bounds__(256) void k_out(const float* __restrict__ v,
                                             const float* __restrict__ x,
                                             const int* __restrict__ cei,
                                             const float* __restrict__ maskp,
                                             const float* __restrict__ invSp,
                                             float* __restrict__ vout,
                                             float* __restrict__ ybuf,   // holds p in, y out
                                             float* __restrict__ yhard) {
    __shared__ float yl[2][EPV];
    __shared__ int   sl[2][EPV];
    int tid  = threadIdx.x;
    int h    = tid >> 7;
    int tsub = tid & 127;
    int j    = blockIdx.x * 2 + h;
    float invS = invSp[0];
    if (tsub < EPV) {
        int e = j + tsub * NVOX;
        yl[h][tsub] = ybuf[e] * invS;
        sl[h][tsub] = cei[e];
    }
    __syncthreads();
    // first argmax (strict > keeps first occurrence == reference segment_min of is_max)
    float mx = yl[h][0]; int am = 0;
#pragma unroll
    for (int q = 1; q < EPV; ++q) {
        float yv = yl[h][q];
        if (yv > mx) { mx = yv; am = q; }
    }
    if (tsub < EPV) {
        int e = j + tsub * NVOX;
        ybuf[e]  = yl[h][tsub];
        yhard[e] = (tsub == am) ? 1.f : 0.f;
    }
    float acc = 0.f;
#pragma unroll
    for (int q = 0; q < EPV; ++q) {
        acc = fmaf(yl[h][q], x[(size_t)sl[h][q] * H + tsub], acc);
    }
    size_t o = (size_t)j * H + tsub;
    vout[o] = fmaf(maskp[j], acc, v[o]);
}

extern "C" void kernel_launch(void* const* d_in, const int* in_sizes, int n_in,
                              void* d_out, int out_size, void* d_ws, size_t ws_size,
                              hipStream_t stream) {
    (void)in_sizes; (void)n_in; (void)out_size; (void)ws_size;
    const float* x   = (const float*)d_in[0];
    const float* v   = (const float*)d_in[1];
    const int*   cei = (const int*)d_in[2];
    const float* Wp  = (const float*)d_in[3];
    const float* bp  = (const float*)d_in[4];
    const float* Wv  = (const float*)d_in[5];
    const float* bv  = (const float*)d_in[6];
    const float* Wm1 = (const float*)d_in[7];
    const float* bm1 = (const float*)d_in[8];
    const float* Wm2 = (const float*)d_in[9];
    const float* bm2 = (const float*)d_in[10];
    const float* th  = (const float*)d_in[11];
    const float* gum = (const float*)d_in[12];

    float* out   = (float*)d_out;
    float* vout  = out;                          // [NV*H]  (holds vv until k_out)
    float* maskp = out + (size_t)NVOX * H;       // [NV]
    float* ybuf  = maskp + NVOX;                 // [E]     (holds p until k_out)
    float* yhard = ybuf + NEDGE;                 // [E]
    float* xp      = yhard;                      // scratch: 65536 floats
    float* partial = yhard + (size_t)NP * H;     // scratch: 50000 floats
    float* invS    = (float*)d_ws;               // 4 bytes of ws

    k_xp<<<NP, 128, 0, stream>>>(x, Wp, bp, xp);
    k_gemm<<<(NVOX + GR - 1) / GR, 256, 0, stream>>>(v, Wv, bv, Wm1, bm1, Wm2, bm2,
                                                     vout, maskp);
    k_edge<<<NVOX, 256, 0, stream>>>(xp, vout, cei, th, gum, ybuf, partial);
    k_reduce<<<1, 1024, 0, stream>>>(partial, invS);
    k_out<<<NVOX / 2, 256, 0, stream>>>(v, x, cei, maskp, invS, vout, ybuf, yhard);
}

// Round 2
// 261.462 us; speedup vs baseline: 1.0867x; 1.0867x over previous
//
#include <hip/hip_runtime.h>

#define H     128
#define NP    512
#define NVOX  50000
#define NEDGE 800000
#define EPV   16        // edges per voxel
#define SLOPE 0.01f
#define GR2   64        // voxel rows per k_main block
#define NBLK  ((NVOX + GR2 - 1) / GR2)   // 782
#define VSTR  132       // padded LDS stride (floats): 132%32=4 -> 2-way max on b128

// tanh(x) = 1 - 2/(exp(2x)+1); robust at +/-inf, ~2-3 ulp
__device__ __forceinline__ float fast_tanh(float xx) {
    float e = __expf(2.f * xx);
    return 1.f - 2.f * __builtin_amdgcn_rcpf(e + 1.f);
}

// ---------------- xp = x @ W_program + b_program  (512 x 128) ----------------
// one block per row, split-K across wave-pairs
__global__ __launch_bounds__(256) void k_xp(const float* __restrict__ x,
                                            const float* __restrict__ Wp,
                                            const float* __restrict__ bp,
                                            float* __restrict__ xpout) {
    __shared__ float part[H];
    int row = blockIdx.x;
    int tid = threadIdx.x;
    int col = tid & 127;
    int kh  = tid >> 7;            // 0 or 1 (uniform per wave)
    int kbase = kh * 64;
    const float* xr = x + (size_t)row * H;
    float acc = 0.f;
#pragma unroll 8
    for (int k = 0; k < 64; ++k) {
        acc = fmaf(xr[kbase + k], Wp[(size_t)(kbase + k) * H + col], acc);
    }
    if (kh == 1) part[col] = acc;
    __syncthreads();
    if (kh == 0) xpout[(size_t)row * H + col] = acc + part[col] + bp[col];
}

// ======= fused: vv = v@Wv+bv (LDS only) ; mask = sigmoid(MLP(v)) ;
//         per-edge p = exp(logit + gumbel) ; per-block partial sum =======
__global__ __launch_bounds__(256, 4) void k_main(
    const float* __restrict__ v,
    const float* __restrict__ Wv,  const float* __restrict__ bv,
    const float* __restrict__ Wm1, const float* __restrict__ bm1,
    const float* __restrict__ Wm2, const float* __restrict__ bm2,
    const float* __restrict__ xp,  const int* __restrict__ cei,
    const float* __restrict__ theta, const float* __restrict__ gum,
    float* __restrict__ mask_out, float* __restrict__ pout,
    float* __restrict__ partial)
{
    __shared__ float vt[GR2 * VSTR];   // v tile, later overwritten with vv tile
    __shared__ float pmbuf[4][64];
    int tid  = threadIdx.x;
    int base = blockIdx.x * GR2;

    // ---- stage v tile (coalesced float4, padded LDS) ----
#pragma unroll
    for (int i = 0; i < 8; ++i) {
        int f  = i * 256 + tid;          // float4-slot id, 2048 total
        int r  = f >> 5, c4 = f & 31;
        int gr = base + r;
        float4 val = (gr < NVOX) ? *(const float4*)&v[(size_t)gr * H + c4 * 4]
                                 : make_float4(0.f, 0.f, 0.f, 0.f);
        *(float4*)&vt[r * VSTR + c4 * 4] = val;
    }
    __syncthreads();

    // ---- phase 2: dual GEMM, lane = row, wave = 32-col group, scalar W ----
    int wave = __builtin_amdgcn_readfirstlane(tid >> 6);
    int lane = tid & 63;                 // row in tile
    int colbase = wave * 32;
    const float* WvB = Wv  + colbase;
    const float* WmB = Wm1 + colbase;

    float aV[32], aM[32];
#pragma unroll
    for (int c = 0; c < 32; ++c) { aV[c] = 0.f; aM[c] = 0.f; }

    for (int k4 = 0; k4 < 32; ++k4) {
        float4 vk = *(const float4*)&vt[lane * VSTR + k4 * 4];
#pragma unroll
        for (int kk = 0; kk < 4; ++kk) {
            float vs = (&vk.x)[kk];
            const float* wv = WvB + (size_t)(k4 * 4 + kk) * H;   // wave-uniform
            const float* wm = WmB + (size_t)(k4 * 4 + kk) * H;   // wave-uniform
#pragma unroll
            for (int c = 0; c < 32; ++c) {
                aV[c] = fmaf(vs, wv[c], aV[c]);
                aM[c] = fmaf(vs, wm[c], aM[c]);
            }
        }
    }
    __syncthreads();                     // all waves done reading vt

    // overwrite vt with vv (+bias): row = lane, cols [colbase, colbase+32)
#pragma unroll
    for (int c4 = 0; c4 < 8; ++c4) {
        float4 o;
        o.x = aV[c4 * 4 + 0] + bv[colbase + c4 * 4 + 0];
        o.y = aV[c4 * 4 + 1] + bv[colbase + c4 * 4 + 1];
        o.z = aV[c4 * 4 + 2] + bv[colbase + c4 * 4 + 2];
        o.w = aV[c4 * 4 + 3] + bv[colbase + c4 * 4 + 3];
        *(float4*)&vt[lane * VSTR + colbase + c4 * 4] = o;
    }

    // mask partial: lrelu(aM + bm1) . Wm2 over this wave's 32 cols
    float pm = 0.f;
#pragma unroll
    for (int c = 0; c < 32; ++c) {
        float m = aM[c] + bm1[colbase + c];
        m = (m >= 0.f) ? m : SLOPE * m;
        pm = fmaf(m, Wm2[colbase + c], pm);
    }
    pmbuf[wave][lane] = pm;
    __syncthreads();                     // vv tile + pmbuf visible
    if (wave == 0) {
        int gr = base + lane;
        if (gr < NVOX) {
            float s = pmbuf[0][lane] + pmbuf[1][lane] + pmbuf[2][lane]
                    + pmbuf[3][lane] + bm2[0];
            mask_out[gr] = __builtin_amdgcn_rcpf(1.f + __expf(-s));
        }
    }

    // ---- phase 3: edges. 8 lanes/edge, 32 edges/pass, 32 passes ----
    int g  = tid >> 3;                   // edge group 0..31
    int lk = tid & 7;
    float th[16];
#pragma unroll
    for (int i = 0; i < 4; ++i) {
        float4 t4 = *(const float4*)&theta[(lk + 8 * i) * 4];
        th[i * 4 + 0] = t4.x; th[i * 4 + 1] = t4.y;
        th[i * 4 + 2] = t4.z; th[i * 4 + 3] = t4.w;
    }
    float psum = 0.f;
    for (int pass = 0; pass < 32; ++pass) {
        int idx = pass * 32 + g;         // 0..1023
        int r   = idx & 63;
        int t   = idx >> 6;              // 0..15
        int vox = base + r;
        bool valid = vox < NVOX;
        int e   = vox + t * NVOX;
        int src = valid ? cei[e] : 0;
        const float4* xr = (const float4*)(xp + (size_t)src * H);
        const float*  vr = &vt[r * VSTR];
        float acc = 0.f;
#pragma unroll
        for (int i = 0; i < 4; ++i) {
            int q = lk + 8 * i;
            float4 a = xr[q];
            float4 b = *(const float4*)&vr[q * 4];
            acc += fast_tanh(a.x + b.x) * th[i * 4 + 0];
            acc += fast_tanh(a.y + b.y) * th[i * 4 + 1];
            acc += fast_tanh(a.z + b.z) * th[i * 4 + 2];
            acc += fast_tanh(a.w + b.w) * th[i * 4 + 3];
        }
        acc += __shfl_xor(acc, 4, 64);
        acc += __shfl_xor(acc, 2, 64);
        acc += __shfl_xor(acc, 1, 64);
        if (lk == 0 && valid) {
            float u   = gum[e];
            float gmb = -__logf(-__logf(u));
            float p   = __expf(acc + gmb);   // TAU=1; z <= ~26, safe in fp32
            pout[e] = p;
            psum   += p;
        }
    }
    // block-reduce psum (deterministic order)
#pragma unroll
    for (int off = 32; off >= 1; off >>= 1) psum += __shfl_xor(psum, off, 64);
    __syncthreads();                     // pmbuf free for reuse
    if (lane == 0) pmbuf[0][wave] = psum;
    __syncthreads();
    if (tid == 0)
        partial[blockIdx.x] = pmbuf[0][0] + pmbuf[0][1] + pmbuf[0][2] + pmbuf[0][3];
}

// ---------------- sum partials -> invS ----------------
__global__ __launch_bounds__(256) void k_reduce(const float* __restrict__ partial,
                                                float* __restrict__ invS) {
    __shared__ float wsum[4];
    int tid = threadIdx.x;
    float s = 0.f;
    for (int i = tid; i < NBLK; i += 256) s += partial[i];
#pragma unroll
    for (int off = 32; off >= 1; off >>= 1) s += __shfl_xor(s, off, 64);
    if ((tid & 63) == 0) wsum[tid >> 6] = s;
    __syncthreads();
    if (tid == 0) invS[0] = 1.f / (wsum[0] + wsum[1] + wsum[2] + wsum[3]);
}

// ---- y = p*invS, per-voxel argmax -> y_hard, summed = sum y*x[src], v_out ----
__global__ __launch_bounds__(256) void k_out(const float* __restrict__ v,
                                             const float* __restrict__ x,
                                             const int* __restrict__ cei,
                                             const float* __restrict__ maskp,
                                             const float* __restrict__ invSp,
                                             float* __restrict__ vout,
                                             float* __restrict__ ybuf,   // p in, y out
                                             float* __restrict__ yhard) {
    __shared__ float yl[2][EPV];
    __shared__ int   sl[2][EPV];
    int tid  = threadIdx.x;
    int h    = tid >> 7;
    int tsub = tid & 127;
    int j    = blockIdx.x * 2 + h;
    float invS = invSp[0];
    if (tsub < EPV) {
        int e = j + tsub * NVOX;
        yl[h][tsub] = ybuf[e] * invS;
        sl[h][tsub] = cei[e];
    }
    __syncthreads();
    // first-max argmax (matches reference segment_min over is_max)
    float mx = yl[h][0]; int am = 0;
#pragma unroll
    for (int q = 1; q < EPV; ++q) {
        float yv = yl[h][q];
        if (yv > mx) { mx = yv; am = q; }
    }
    if (tsub < EPV) {
        int e = j + tsub * NVOX;
        ybuf[e]  = yl[h][tsub];
        yhard[e] = (tsub == am) ? 1.f : 0.f;
    }
    float acc = 0.f;
#pragma unroll
    for (int q = 0; q < EPV; ++q) {
        acc = fmaf(yl[h][q], x[(size_t)sl[h][q] * H + tsub], acc);
    }
    size_t o = (size_t)j * H + tsub;
    vout[o] = fmaf(maskp[j], acc, v[o]);
}

extern "C" void kernel_launch(void* const* d_in, const int* in_sizes, int n_in,
                              void* d_out, int out_size, void* d_ws, size_t ws_size,
                              hipStream_t stream) {
    (void)in_sizes; (void)n_in; (void)out_size; (void)ws_size;
    const float* x   = (const float*)d_in[0];
    const float* v   = (const float*)d_in[1];
    const int*   cei = (const int*)d_in[2];
    const float* Wp  = (const float*)d_in[3];
    const float* bp  = (const float*)d_in[4];
    const float* Wv  = (const float*)d_in[5];
    const float* bv  = (const float*)d_in[6];
    const float* Wm1 = (const float*)d_in[7];
    const float* bm1 = (const float*)d_in[8];
    const float* Wm2 = (const float*)d_in[9];
    const float* bm2 = (const float*)d_in[10];
    const float* th  = (const float*)d_in[11];
    const float* gum = (const float*)d_in[12];

    float* out   = (float*)d_out;
    float* vout  = out;                          // [NV*H]
    float* maskp = out + (size_t)NVOX * H;       // [NV]
    float* ybuf  = maskp + NVOX;                 // [E]  (p until k_out)
    float* yhard = ybuf + NEDGE;                 // [E]
    float* xp      = yhard;                      // scratch: 65536 floats (consumed pre-k_out)
    float* partial = yhard + (size_t)NP * H;     // scratch: NBLK floats
    float* invS    = (float*)d_ws;               // 4 bytes

    k_xp<<<NP, 256, 0, stream>>>(x, Wp, bp, xp);
    k_main<<<NBLK, 256, 0, stream>>>(v, Wv, bv, Wm1, bm1, Wm2, bm2,
                                     xp, cei, th, gum, maskp, ybuf, partial);
    k_reduce<<<1, 256, 0, stream>>>(partial, invS);
    k_out<<<NVOX / 2, 256, 0, stream>>>(v, x, cei, maskp, invS, vout, ybuf, yhard);
}

// Round 3
// 223.274 us; speedup vs baseline: 1.2726x; 1.1710x over previous
//
#include <hip/hip_runtime.h>

#define H     128
#define NP    512
#define NVOX  50000
#define NEDGE 800000
#define EPV   16
#define SLOPE 0.01f
#define GR    32                          // voxel rows per k_main block
#define NBLK  ((NVOX + GR - 1) / GR)      // 1563
#define STRH  136                         // padded f16 LDS stride (halves)
#define VSTR  132                         // padded f32 LDS stride (floats)
#define C1    2.8853900817779268f         // 2*log2(e)
#define LOG2E 1.4426950408889634f

typedef _Float16 h16;
typedef __attribute__((ext_vector_type(4))) _Float16 h16x4;
typedef __attribute__((ext_vector_type(8))) _Float16 h16x8;
typedef __attribute__((ext_vector_type(4))) float    f32x4;

// ---- split Wv into f16 hi/lo (transposed [n][k]) + Wm1 f16 (transposed) ----
__global__ __launch_bounds__(256) void k_wsplit(const float* __restrict__ Wv,
                                                const float* __restrict__ Wm1,
                                                h16* __restrict__ WvThi,
                                                h16* __restrict__ WvTlo,
                                                h16* __restrict__ Wm1T) {
    int idx = blockIdx.x * 256 + threadIdx.x;    // grid 128 -> 32768
    if (idx < 16384) {
        int k = idx >> 7, n = idx & 127;
        float w = Wv[idx];                       // Wv[k][n]
        h16 hi = (h16)w;
        WvThi[n * H + k] = hi;
        WvTlo[n * H + k] = (h16)(w - (float)hi);
    } else {
        int j = idx - 16384;
        int k = j >> 7, n = j & 127;
        Wm1T[n * H + k] = (h16)Wm1[j];
    }
}

// ---------------- xp' = (x @ W_program + b_program) * C1  (512 x 128) ----------------
__global__ __launch_bounds__(256) void k_xp(const float* __restrict__ x,
                                            const float* __restrict__ Wp,
                                            const float* __restrict__ bp,
                                            float* __restrict__ xpout) {
    __shared__ float part[H];
    int row = blockIdx.x;
    int tid = threadIdx.x;
    int col = tid & 127;
    int kh  = tid >> 7;
    int kbase = kh * 64;
    const float* xr = x + (size_t)row * H;
    float acc = 0.f;
#pragma unroll 8
    for (int k = 0; k < 64; ++k)
        acc = fmaf(xr[kbase + k], Wp[(size_t)(kbase + k) * H + col], acc);
    if (kh == 1) part[col] = acc;
    __syncthreads();
    if (kh == 0) xpout[(size_t)row * H + col] = (acc + part[col] + bp[col]) * C1;
}

// ======= fused: vv = (v@Wv+bv)*C1 via split-f16 MFMA (LDS only);
//         mask = sigmoid(MLP(v)); per-edge p = exp(logit+gumbel); partial sums =======
__global__ __launch_bounds__(256) void k_main(
    const float* __restrict__ v,
    const float* __restrict__ bv,  const float* __restrict__ bm1,
    const float* __restrict__ Wm2, const float* __restrict__ bm2,
    const h16* __restrict__ WvThi, const h16* __restrict__ WvTlo,
    const h16* __restrict__ Wm1T,
    const float* __restrict__ xp,  const int* __restrict__ cei,
    const float* __restrict__ theta, const float* __restrict__ gum,
    float* __restrict__ mask_out, float* __restrict__ pout,
    float* __restrict__ partial)
{
    __shared__ __align__(16) char ldsbuf[GR * STRH * 2 * 2];  // 17408 B
    h16*   vh = (h16*)ldsbuf;            // [GR][STRH]
    h16*   vl = vh + GR * STRH;
    float* vt = (float*)ldsbuf;          // [GR][VSTR] f32, reused after GEMM
    __shared__ float pmbuf[4][GR];
    __shared__ float psums[4];

    int tid  = threadIdx.x;
    int base = blockIdx.x * GR;

    // ---- stage v tile, split into f16 hi/lo ----
#pragma unroll
    for (int i = 0; i < 4; ++i) {
        int f  = i * 256 + tid;          // 1024 float4 slots
        int r  = f >> 5, c4 = f & 31;
        int gr = base + r;
        float4 val = (gr < NVOX) ? *(const float4*)&v[(size_t)gr * H + c4 * 4]
                                 : make_float4(0.f, 0.f, 0.f, 0.f);
        h16x4 hi, lo;
        hi.x = (h16)val.x; lo.x = (h16)(val.x - (float)hi.x);
        hi.y = (h16)val.y; lo.y = (h16)(val.y - (float)hi.y);
        hi.z = (h16)val.z; lo.z = (h16)(val.z - (float)hi.z);
        hi.w = (h16)val.w; lo.w = (h16)(val.w - (float)hi.w);
        *(h16x4*)&vh[r * STRH + c4 * 4] = hi;
        *(h16x4*)&vl[r * STRH + c4 * 4] = lo;
    }
    __syncthreads();

    // ---- dual GEMM via MFMA 16x16x32 f16 ----
    int wave = tid >> 6, lane = tid & 63;
    int m16 = lane & 15, quad = lane >> 4;
    int cb = wave * 32;

    f32x4 aV[2][2], aM[2][2];
#pragma unroll
    for (int rt = 0; rt < 2; ++rt)
#pragma unroll
        for (int ct = 0; ct < 2; ++ct) { aV[rt][ct] = (f32x4)0.f; aM[rt][ct] = (f32x4)0.f; }

#pragma unroll
    for (int kc = 0; kc < 4; ++kc) {
        int kofs = kc * 32 + quad * 8;
        h16x8 ah[2], al[2];
#pragma unroll
        for (int rt = 0; rt < 2; ++rt) {
            int row = rt * 16 + m16;
            ah[rt] = *(const h16x8*)&vh[row * STRH + kofs];
            al[rt] = *(const h16x8*)&vl[row * STRH + kofs];
        }
#pragma unroll
        for (int ct = 0; ct < 2; ++ct) {
            int n = cb + ct * 16 + m16;
            h16x8 bh = *(const h16x8*)&WvThi[n * H + kofs];
            h16x8 bl = *(const h16x8*)&WvTlo[n * H + kofs];
            h16x8 bm = *(const h16x8*)&Wm1T[n * H + kofs];
#pragma unroll
            for (int rt = 0; rt < 2; ++rt) {
                aV[rt][ct] = __builtin_amdgcn_mfma_f32_16x16x32_f16(ah[rt], bh, aV[rt][ct], 0, 0, 0);
                aV[rt][ct] = __builtin_amdgcn_mfma_f32_16x16x32_f16(al[rt], bh, aV[rt][ct], 0, 0, 0);
                aV[rt][ct] = __builtin_amdgcn_mfma_f32_16x16x32_f16(ah[rt], bl, aV[rt][ct], 0, 0, 0);
                aM[rt][ct] = __builtin_amdgcn_mfma_f32_16x16x32_f16(ah[rt], bm, aM[rt][ct], 0, 0, 0);
            }
        }
    }
    __syncthreads();                     // vh/vl fully consumed

    // ---- write vv tile (prescaled by C1) + mask partials ----
    float pml[2][4];
#pragma unroll
    for (int rt = 0; rt < 2; ++rt)
#pragma unroll
        for (int reg = 0; reg < 4; ++reg) pml[rt][reg] = 0.f;
#pragma unroll
    for (int ct = 0; ct < 2; ++ct) {
        int col = cb + ct * 16 + m16;
        float bvc = bv[col], bmc = bm1[col], w2c = Wm2[col];
#pragma unroll
        for (int rt = 0; rt < 2; ++rt)
#pragma unroll
            for (int reg = 0; reg < 4; ++reg) {
                int row = rt * 16 + quad * 4 + reg;
                vt[row * VSTR + col] = (aV[rt][ct][reg] + bvc) * C1;
                float m = aM[rt][ct][reg] + bmc;
                m = (m >= 0.f) ? m : SLOPE * m;
                pml[rt][reg] = fmaf(m, w2c, pml[rt][reg]);
            }
    }
    // reduce mask partials over the 16 m16-lanes (same rows)
#pragma unroll
    for (int off = 8; off >= 1; off >>= 1)
#pragma unroll
        for (int rt = 0; rt < 2; ++rt)
#pragma unroll
            for (int reg = 0; reg < 4; ++reg)
                pml[rt][reg] += __shfl_xor(pml[rt][reg], off, 64);
    if (m16 == 0) {
#pragma unroll
        for (int rt = 0; rt < 2; ++rt)
#pragma unroll
            for (int reg = 0; reg < 4; ++reg)
                pmbuf[wave][rt * 16 + quad * 4 + reg] = pml[rt][reg];
    }
    __syncthreads();
    if (wave == 0 && lane < GR) {
        int gr = base + lane;
        if (gr < NVOX) {
            float s = pmbuf[0][lane] + pmbuf[1][lane] + pmbuf[2][lane]
                    + pmbuf[3][lane] + bm2[0];
            mask_out[gr] = __builtin_amdgcn_rcpf(1.f + __expf(-s));
        }
    }

    // ---- edges: 8 lanes/edge, 32 edges/pass, 16 passes ----
    int g = tid >> 3, lk = tid & 7;
    float th2[16], thsum = 0.f;
#pragma unroll
    for (int i = 0; i < 4; ++i) {
        float4 t4 = *(const float4*)&theta[(lk + 8 * i) * 4];
        th2[i * 4 + 0] = -2.f * t4.x; th2[i * 4 + 1] = -2.f * t4.y;
        th2[i * 4 + 2] = -2.f * t4.z; th2[i * 4 + 3] = -2.f * t4.w;
        thsum += t4.x + t4.y + t4.z + t4.w;
    }
    float psum = 0.f;
    for (int pass = 0; pass < 16; ++pass) {
        int idx = pass * 32 + g;         // 0..511
        int r   = idx & 31;
        int t   = idx >> 5;              // 0..15
        int vox = base + r;
        bool valid = vox < NVOX;
        int e   = vox + t * NVOX;
        int src = valid ? cei[e] : 0;
        const float4* xr = (const float4*)(xp + (size_t)src * H);
        const float*  vr = &vt[r * VSTR];
        float acc = thsum;               // acc = sum(theta) - 2*sum(theta*r) = theta.tanh
#pragma unroll
        for (int i = 0; i < 4; ++i) {
            int q = lk + 8 * i;
            float4 a = xr[q];
            float4 b = *(const float4*)&vr[q * 4];
            acc = fmaf(th2[i*4+0], __builtin_amdgcn_rcpf(exp2f(a.x + b.x) + 1.f), acc);
            acc = fmaf(th2[i*4+1], __builtin_amdgcn_rcpf(exp2f(a.y + b.y) + 1.f), acc);
            acc = fmaf(th2[i*4+2], __builtin_amdgcn_rcpf(exp2f(a.z + b.z) + 1.f), acc);
            acc = fmaf(th2[i*4+3], __builtin_amdgcn_rcpf(exp2f(a.w + b.w) + 1.f), acc);
        }
        acc += __shfl_xor(acc, 4, 64);
        acc += __shfl_xor(acc, 2, 64);
        acc += __shfl_xor(acc, 1, 64);
        if (lk == 0 && valid) {
            float u   = gum[e];
            float gmb = -__logf(-__logf(u));
            float p   = exp2f((acc + gmb) * LOG2E);   // TAU=1, z bounded, fp32-safe
            pout[e] = p;
            psum   += p;
        }
    }
#pragma unroll
    for (int off = 32; off >= 1; off >>= 1) psum += __shfl_xor(psum, off, 64);
    __syncthreads();
    if (lane == 0) psums[wave] = psum;
    __syncthreads();
    if (tid == 0)
        partial[blockIdx.x] = psums[0] + psums[1] + psums[2] + psums[3];
}

// ---------------- sum partials -> invS ----------------
__global__ __launch_bounds__(256) void k_reduce(const float* __restrict__ partial,
                                                float* __restrict__ invS) {
    __shared__ float wsum[4];
    int tid = threadIdx.x;
    float s = 0.f;
    for (int i = tid; i < NBLK; i += 256) s += partial[i];
#pragma unroll
    for (int off = 32; off >= 1; off >>= 1) s += __shfl_xor(s, off, 64);
    if ((tid & 63) == 0) wsum[tid >> 6] = s;
    __syncthreads();
    if (tid == 0) invS[0] = 1.f / (wsum[0] + wsum[1] + wsum[2] + wsum[3]);
}

// ---- y, y_hard, summed, v_out — coalesced tiles of 32 voxels ----
__global__ __launch_bounds__(256) void k_out(const float* __restrict__ v,
                                             const float* __restrict__ x,
                                             const int* __restrict__ cei,
                                             const float* __restrict__ maskp,
                                             const float* __restrict__ invSp,
                                             float* __restrict__ vout,
                                             float* __restrict__ ybuf,   // p in, y out
                                             float* __restrict__ yhard) {
    __shared__ float yt[EPV][32];
    __shared__ int   st[EPV][32];
    __shared__ int   am[32];
    int tid  = threadIdx.x;
    int base = blockIdx.x * 32;
    float invS = invSp[0];
#pragma unroll
    for (int it = 0; it < 2; ++it) {
        int t = (tid >> 5) + 8 * it, c = tid & 31;
        int vox = base + c;
        if (vox < NVOX) {
            int e = vox + t * NVOX;
            float y = ybuf[e] * invS;
            yt[t][c] = y;
            st[t][c] = cei[e];
            ybuf[e]  = y;
        }
    }
    __syncthreads();
    if (tid < 32 && base + tid < NVOX) {
        int c = tid;
        float mx = yt[0][c]; int a = 0;
#pragma unroll
        for (int t = 1; t < EPV; ++t) {
            float yv = yt[t][c];
            if (yv > mx) { mx = yv; a = t; }   // first-max = reference semantics
        }
        am[c] = a;
    }
    __syncthreads();
#pragma unroll
    for (int it = 0; it < 2; ++it) {
        int t = (tid >> 5) + 8 * it, c = tid & 31;
        int vox = base + c;
        if (vox < NVOX) yhard[vox + t * NVOX] = (t == am[c]) ? 1.f : 0.f;
    }
    int col = tid & 127, hf = tid >> 7;
    for (int vx = hf; vx < 32; vx += 2) {
        int vox = base + vx;
        if (vox >= NVOX) break;
        float acc = 0.f;
#pragma unroll
        for (int t = 0; t < EPV; ++t)
            acc = fmaf(yt[t][vx], x[(size_t)st[t][vx] * H + col], acc);
        size_t o = (size_t)vox * H + col;
        vout[o] = fmaf(maskp[vox], acc, v[o]);
    }
}

extern "C" void kernel_launch(void* const* d_in, const int* in_sizes, int n_in,
                              void* d_out, int out_size, void* d_ws, size_t ws_size,
                              hipStream_t stream) {
    (void)in_sizes; (void)n_in; (void)out_size; (void)ws_size;
    const float* x   = (const float*)d_in[0];
    const float* v   = (const float*)d_in[1];
    const int*   cei = (const int*)d_in[2];
    const float* Wp  = (const float*)d_in[3];
    const float* bp  = (const float*)d_in[4];
    const float* Wv  = (const float*)d_in[5];
    const float* bv  = (const float*)d_in[6];
    const float* Wm1 = (const float*)d_in[7];
    const float* bm1 = (const float*)d_in[8];
    const float* Wm2 = (const float*)d_in[9];
    const float* bm2 = (const float*)d_in[10];
    const float* th  = (const float*)d_in[11];
    const float* gum = (const float*)d_in[12];

    float* out   = (float*)d_out;
    float* vout  = out;                          // [NV*H]
    float* maskp = out + (size_t)NVOX * H;       // [NV]
    float* ybuf  = maskp + NVOX;                 // [E]  (p until k_out)
    float* yhard = ybuf + NEDGE;                 // [E]  (scratch until k_out)
    float* xp      = yhard;                      // 65536 floats
    float* partial = yhard + 65536;              // NBLK floats
    h16*   WvThi   = (h16*)(yhard + 67104);      // 16384 h16 (16B-aligned)
    h16*   WvTlo   = WvThi + 16384;
    h16*   Wm1T    = WvThi + 32768;
    float* invS    = (float*)d_ws;               // 4 bytes

    k_wsplit<<<128, 256, 0, stream>>>(Wv, Wm1, WvThi, WvTlo, Wm1T);
    k_xp<<<NP, 256, 0, stream>>>(x, Wp, bp, xp);
    k_main<<<NBLK, 256, 0, stream>>>(v, bv, bm1, Wm2, bm2, WvThi, WvTlo, Wm1T,
                                     xp, cei, th, gum, maskp, ybuf, partial);
    k_reduce<<<1, 256, 0, stream>>>(partial, invS);
    k_out<<<(NVOX + 31) / 32, 256, 0, stream>>>(v, x, cei, maskp, invS, vout, ybuf, yhard);
}

// Round 4
// 187.733 us; speedup vs baseline: 1.5135x; 1.1893x over previous
//
#include <hip/hip_runtime.h>

#define H     128
#define NP    512
#define NVOX  50000
#define NEDGE 800000
#define EPV   16
#define SLOPE 0.01f
#define GR    32                          // voxel rows per k_main block
#define NBLK  ((NVOX + GR - 1) / GR)      // 1563
#define STRH  136                         // padded f16 LDS stride (halves)
#define VSTR  132                         // padded f32 LDS stride (floats)
#define C1    2.8853900817779268f         // 2*log2(e)
#define LOG2E 1.4426950408889634f
#define LN2   0.6931471805599453f

#define EXP2(x) __builtin_amdgcn_exp2f(x)   // raw v_exp_f32
#define LOG2(x) __builtin_amdgcn_logf(x)    // raw v_log_f32
#define RCP(x)  __builtin_amdgcn_rcpf(x)    // raw v_rcp_f32

typedef _Float16 h16;
typedef __attribute__((ext_vector_type(4))) _Float16 h16x4;
typedef __attribute__((ext_vector_type(8))) _Float16 h16x8;
typedef __attribute__((ext_vector_type(4))) float    f32x4;

// ==== merged: blocks [0,NP) -> xp' = (x@Wp+bp)*C1 ; blocks [NP,NP+128) -> W split ====
__global__ __launch_bounds__(256) void k_pre(const float* __restrict__ x,
                                             const float* __restrict__ Wp,
                                             const float* __restrict__ bp,
                                             const float* __restrict__ Wv,
                                             const float* __restrict__ Wm1,
                                             float* __restrict__ xpout,
                                             h16* __restrict__ WvThi,
                                             h16* __restrict__ WvTlo,
                                             h16* __restrict__ Wm1T) {
    __shared__ float part[H];
    int bid = blockIdx.x;
    int tid = threadIdx.x;
    if (bid < NP) {
        int row = bid;
        int col = tid & 127;
        int kh  = tid >> 7;
        int kbase = kh * 64;
        const float* xr = x + (size_t)row * H;
        float acc = 0.f;
#pragma unroll 8
        for (int k = 0; k < 64; ++k)
            acc = fmaf(xr[kbase + k], Wp[(size_t)(kbase + k) * H + col], acc);
        if (kh == 1) part[col] = acc;
        __syncthreads();
        if (kh == 0) xpout[(size_t)row * H + col] = (acc + part[col] + bp[col]) * C1;
    } else {
        int idx = (bid - NP) * 256 + tid;            // 128 blocks -> 32768
        if (idx < 16384) {
            int k = idx >> 7, n = idx & 127;
            float w = Wv[idx];                       // Wv[k][n]
            h16 hi = (h16)w;
            WvThi[n * H + k] = hi;
            WvTlo[n * H + k] = (h16)(w - (float)hi);
        } else {
            int j = idx - 16384;
            int k = j >> 7, n = j & 127;
            Wm1T[n * H + k] = (h16)Wm1[j];
        }
    }
}

// ======= fused: vv = (v@Wv+bv)*C1 via split-f16 MFMA (LDS only);
//         mask = sigmoid(MLP(v)); per-edge p = exp(logit+gumbel); partial sums =======
__global__ __launch_bounds__(256) void k_main(
    const float* __restrict__ v,
    const float* __restrict__ bv,  const float* __restrict__ bm1,
    const float* __restrict__ Wm2, const float* __restrict__ bm2,
    const h16* __restrict__ WvThi, const h16* __restrict__ WvTlo,
    const h16* __restrict__ Wm1T,
    const float* __restrict__ xp,  const int* __restrict__ cei,
    const float* __restrict__ theta, const float* __restrict__ gum,
    float* __restrict__ mask_out, float* __restrict__ pout,
    float* __restrict__ partial)
{
    __shared__ __align__(16) char ldsbuf[GR * STRH * 2 * 2];  // 17408 B
    h16*   vh = (h16*)ldsbuf;            // [GR][STRH]
    h16*   vl = vh + GR * STRH;
    float* vt = (float*)ldsbuf;          // [GR][VSTR] f32, reused after GEMM
    __shared__ float pmbuf[4][GR];
    __shared__ float psums[4];

    int tid  = threadIdx.x;
    int base = blockIdx.x * GR;

    // ---- stage v tile, split into f16 hi/lo ----
#pragma unroll
    for (int i = 0; i < 4; ++i) {
        int f  = i * 256 + tid;
        int r  = f >> 5, c4 = f & 31;
        int gr = base + r;
        float4 val = (gr < NVOX) ? *(const float4*)&v[(size_t)gr * H + c4 * 4]
                                 : make_float4(0.f, 0.f, 0.f, 0.f);
        h16x4 hi, lo;
        hi.x = (h16)val.x; lo.x = (h16)(val.x - (float)hi.x);
        hi.y = (h16)val.y; lo.y = (h16)(val.y - (float)hi.y);
        hi.z = (h16)val.z; lo.z = (h16)(val.z - (float)hi.z);
        hi.w = (h16)val.w; lo.w = (h16)(val.w - (float)hi.w);
        *(h16x4*)&vh[r * STRH + c4 * 4] = hi;
        *(h16x4*)&vl[r * STRH + c4 * 4] = lo;
    }
    __syncthreads();

    // ---- dual GEMM via MFMA 16x16x32 f16 (split hi/lo for Wv path) ----
    int wave = tid >> 6, lane = tid & 63;
    int m16 = lane & 15, quad = lane >> 4;
    int cb = wave * 32;

    f32x4 aV[2][2], aM[2][2];
#pragma unroll
    for (int rt = 0; rt < 2; ++rt)
#pragma unroll
        for (int ct = 0; ct < 2; ++ct) { aV[rt][ct] = (f32x4)0.f; aM[rt][ct] = (f32x4)0.f; }

#pragma unroll
    for (int kc = 0; kc < 4; ++kc) {
        int kofs = kc * 32 + quad * 8;
        h16x8 ah[2], al[2];
#pragma unroll
        for (int rt = 0; rt < 2; ++rt) {
            int row = rt * 16 + m16;
            ah[rt] = *(const h16x8*)&vh[row * STRH + kofs];
            al[rt] = *(const h16x8*)&vl[row * STRH + kofs];
        }
#pragma unroll
        for (int ct = 0; ct < 2; ++ct) {
            int n = cb + ct * 16 + m16;
            h16x8 bh = *(const h16x8*)&WvThi[n * H + kofs];
            h16x8 bl = *(const h16x8*)&WvTlo[n * H + kofs];
            h16x8 bm = *(const h16x8*)&Wm1T[n * H + kofs];
#pragma unroll
            for (int rt = 0; rt < 2; ++rt) {
                aV[rt][ct] = __builtin_amdgcn_mfma_f32_16x16x32_f16(ah[rt], bh, aV[rt][ct], 0, 0, 0);
                aV[rt][ct] = __builtin_amdgcn_mfma_f32_16x16x32_f16(al[rt], bh, aV[rt][ct], 0, 0, 0);
                aV[rt][ct] = __builtin_amdgcn_mfma_f32_16x16x32_f16(ah[rt], bl, aV[rt][ct], 0, 0, 0);
                aM[rt][ct] = __builtin_amdgcn_mfma_f32_16x16x32_f16(ah[rt], bm, aM[rt][ct], 0, 0, 0);
            }
        }
    }
    __syncthreads();                     // vh/vl fully consumed

    // ---- write vv tile (prescaled by C1) + mask partials ----
    float pml[2][4];
#pragma unroll
    for (int rt = 0; rt < 2; ++rt)
#pragma unroll
        for (int reg = 0; reg < 4; ++reg) pml[rt][reg] = 0.f;
#pragma unroll
    for (int ct = 0; ct < 2; ++ct) {
        int col = cb + ct * 16 + m16;
        float bvc = bv[col], bmc = bm1[col], w2c = Wm2[col];
#pragma unroll
        for (int rt = 0; rt < 2; ++rt)
#pragma unroll
            for (int reg = 0; reg < 4; ++reg) {
                int row = rt * 16 + quad * 4 + reg;
                vt[row * VSTR + col] = (aV[rt][ct][reg] + bvc) * C1;
                float m = aM[rt][ct][reg] + bmc;
                m = (m >= 0.f) ? m : SLOPE * m;
                pml[rt][reg] = fmaf(m, w2c, pml[rt][reg]);
            }
    }
#pragma unroll
    for (int off = 8; off >= 1; off >>= 1)
#pragma unroll
        for (int rt = 0; rt < 2; ++rt)
#pragma unroll
            for (int reg = 0; reg < 4; ++reg)
                pml[rt][reg] += __shfl_xor(pml[rt][reg], off, 64);
    if (m16 == 0) {
#pragma unroll
        for (int rt = 0; rt < 2; ++rt)
#pragma unroll
            for (int reg = 0; reg < 4; ++reg)
                pmbuf[wave][rt * 16 + quad * 4 + reg] = pml[rt][reg];
    }
    __syncthreads();                     // vt + pmbuf visible
    if (wave == 0 && lane < GR) {
        int gr = base + lane;
        if (gr < NVOX) {
            float s = pmbuf[0][lane] + pmbuf[1][lane] + pmbuf[2][lane]
                    + pmbuf[3][lane] + bm2[0];
            mask_out[gr] = RCP(1.f + EXP2(-s * LOG2E));
        }
    }

    // ---- edges: 8 lanes/edge, group g owns voxel base+g, t = 0..15 ----
    int g = tid >> 3, lk = tid & 7;
    float th2[16], thsum = 0.f;
#pragma unroll
    for (int i = 0; i < 4; ++i) {
        float4 t4 = *(const float4*)&theta[(lk + 8 * i) * 4];
        th2[i * 4 + 0] = -2.f * t4.x; th2[i * 4 + 1] = -2.f * t4.y;
        th2[i * 4 + 2] = -2.f * t4.z; th2[i * 4 + 3] = -2.f * t4.w;
        thsum += t4.x + t4.y + t4.z + t4.w;
    }
    int vox = base + g;
    bool valid = vox < NVOX;
    const float* vr = &vt[g * VSTR];
    float4 b0 = *(const float4*)&vr[(lk +  0) * 4];   // row constant across passes
    float4 b1 = *(const float4*)&vr[(lk +  8) * 4];
    float4 b2 = *(const float4*)&vr[(lk + 16) * 4];
    float4 b3 = *(const float4*)&vr[(lk + 24) * 4];

    float psum = 0.f;
    for (int t = 0; t < EPV; ++t) {
        int e   = vox + t * NVOX;
        int src = valid ? cei[e] : 0;
        const float4* xr = (const float4*)(xp + (size_t)src * H);
        float4 a0 = xr[lk], a1 = xr[lk + 8], a2 = xr[lk + 16], a3 = xr[lk + 24];
        float acc0 = thsum, acc1 = 0.f;
        acc0 = fmaf(th2[ 0], RCP(EXP2(a0.x + b0.x) + 1.f), acc0);
        acc1 = fmaf(th2[ 1], RCP(EXP2(a0.y + b0.y) + 1.f), acc1);
        acc0 = fmaf(th2[ 2], RCP(EXP2(a0.z + b0.z) + 1.f), acc0);
        acc1 = fmaf(th2[ 3], RCP(EXP2(a0.w + b0.w) + 1.f), acc1);
        acc0 = fmaf(th2[ 4], RCP(EXP2(a1.x + b1.x) + 1.f), acc0);
        acc1 = fmaf(th2[ 5], RCP(EXP2(a1.y + b1.y) + 1.f), acc1);
        acc0 = fmaf(th2[ 6], RCP(EXP2(a1.z + b1.z) + 1.f), acc0);
        acc1 = fmaf(th2[ 7], RCP(EXP2(a1.w + b1.w) + 1.f), acc1);
        acc0 = fmaf(th2[ 8], RCP(EXP2(a2.x + b2.x) + 1.f), acc0);
        acc1 = fmaf(th2[ 9], RCP(EXP2(a2.y + b2.y) + 1.f), acc1);
        acc0 = fmaf(th2[10], RCP(EXP2(a2.z + b2.z) + 1.f), acc0);
        acc1 = fmaf(th2[11], RCP(EXP2(a2.w + b2.w) + 1.f), acc1);
        acc0 = fmaf(th2[12], RCP(EXP2(a3.x + b3.x) + 1.f), acc0);
        acc1 = fmaf(th2[13], RCP(EXP2(a3.y + b3.y) + 1.f), acc1);
        acc0 = fmaf(th2[14], RCP(EXP2(a3.z + b3.z) + 1.f), acc0);
        acc1 = fmaf(th2[15], RCP(EXP2(a3.w + b3.w) + 1.f), acc1);
        float acc = acc0 + acc1;
        acc += __shfl_xor(acc, 4, 64);
        acc += __shfl_xor(acc, 2, 64);
        acc += __shfl_xor(acc, 1, 64);
        if (lk == 0 && valid) {
            float u  = gum[e];
            float l1 = LOG2(u);                       // log2(u) < 0
            float t1 = -LN2 * l1;                     // -ln(u) > 0
            float gm = -LN2 * LOG2(t1);               // -ln(-ln u)
            float p  = EXP2((acc + gm) * LOG2E);      // TAU=1, z bounded, fp32-safe
            pout[e] = p;
            psum   += p;
        }
    }
#pragma unroll
    for (int off = 32; off >= 1; off >>= 1) psum += __shfl_xor(psum, off, 64);
    __syncthreads();
    if (lane == 0) psums[wave] = psum;
    __syncthreads();
    if (tid == 0)
        partial[blockIdx.x] = psums[0] + psums[1] + psums[2] + psums[3];
}

// ---------------- sum partials -> invS ----------------
__global__ __launch_bounds__(256) void k_reduce(const float* __restrict__ partial,
                                                float* __restrict__ invS) {
    __shared__ float wsum[4];
    int tid = threadIdx.x;
    float s = 0.f;
    for (int i = tid; i < NBLK; i += 256) s += partial[i];
#pragma unroll
    for (int off = 32; off >= 1; off >>= 1) s += __shfl_xor(s, off, 64);
    if ((tid & 63) == 0) wsum[tid >> 6] = s;
    __syncthreads();
    if (tid == 0) invS[0] = 1.f / (wsum[0] + wsum[1] + wsum[2] + wsum[3]);
}

// ---- y, y_hard, summed, v_out — coalesced tiles of 32 voxels, float4 accum ----
__global__ __launch_bounds__(256) void k_out(const float* __restrict__ v,
                                             const float* __restrict__ x,
                                             const int* __restrict__ cei,
                                             const float* __restrict__ maskp,
                                             const float* __restrict__ invSp,
                                             float* __restrict__ vout,
                                             float* __restrict__ ybuf,   // p in, y out
                                             float* __restrict__ yhard) {
    __shared__ float yt[EPV][32];
    __shared__ int   st[EPV][32];
    __shared__ int   am[32];
    int tid  = threadIdx.x;
    int base = blockIdx.x * 32;
    float invS = invSp[0];
#pragma unroll
    for (int it = 0; it < 2; ++it) {
        int idx = it * 256 + tid;
        int t = idx >> 5, c = idx & 31;
        int vox = base + c;
        if (vox < NVOX) {
            int e = vox + t * NVOX;
            float y = ybuf[e] * invS;
            yt[t][c] = y;
            st[t][c] = cei[e];
            ybuf[e]  = y;
        }
    }
    __syncthreads();
    if (tid < 32 && base + tid < NVOX) {
        int c = tid;
        float mx = yt[0][c]; int a = 0;
#pragma unroll
        for (int t = 1; t < EPV; ++t) {
            float yv = yt[t][c];
            if (yv > mx) { mx = yv; a = t; }   // first-max = reference semantics
        }
        am[c] = a;
    }
    __syncthreads();
#pragma unroll
    for (int it = 0; it < 2; ++it) {
        int idx = it * 256 + tid;
        int t = idx >> 5, c = idx & 31;
        int vox = base + c;
        if (vox < NVOX) yhard[vox + t * NVOX] = (t == am[c]) ? 1.f : 0.f;
    }
    // summed + v_out: 8 voxel-slots x 32 float4-columns
    int c4 = (tid & 31) * 4;
    for (int vx = tid >> 5; vx < 32; vx += 8) {
        int vox = base + vx;
        if (vox >= NVOX) break;
        float4 acc = make_float4(0.f, 0.f, 0.f, 0.f);
#pragma unroll
        for (int t = 0; t < EPV; ++t) {
            float y = yt[t][vx];                              // LDS broadcast
            const float4 xv = *(const float4*)&x[(size_t)st[t][vx] * H + c4];
            acc.x = fmaf(y, xv.x, acc.x);
            acc.y = fmaf(y, xv.y, acc.y);
            acc.z = fmaf(y, xv.z, acc.z);
            acc.w = fmaf(y, xv.w, acc.w);
        }
        float m = maskp[vox];
        const float4 vv = *(const float4*)&v[(size_t)vox * H + c4];
        float4 o;
        o.x = fmaf(m, acc.x, vv.x);
        o.y = fmaf(m, acc.y, vv.y);
        o.z = fmaf(m, acc.z, vv.z);
        o.w = fmaf(m, acc.w, vv.w);
        *(float4*)&vout[(size_t)vox * H + c4] = o;
    }
}

extern "C" void kernel_launch(void* const* d_in, const int* in_sizes, int n_in,
                              void* d_out, int out_size, void* d_ws, size_t ws_size,
                              hipStream_t stream) {
    (void)in_sizes; (void)n_in; (void)out_size; (void)ws_size;
    const float* x   = (const float*)d_in[0];
    const float* v   = (const float*)d_in[1];
    const int*   cei = (const int*)d_in[2];
    const float* Wp  = (const float*)d_in[3];
    const float* bp  = (const float*)d_in[4];
    const float* Wv  = (const float*)d_in[5];
    const float* bv  = (const float*)d_in[6];
    const float* Wm1 = (const float*)d_in[7];
    const float* bm1 = (const float*)d_in[8];
    const float* Wm2 = (const float*)d_in[9];
    const float* bm2 = (const float*)d_in[10];
    const float* th  = (const float*)d_in[11];
    const float* gum = (const float*)d_in[12];

    float* out   = (float*)d_out;
    float* vout  = out;                          // [NV*H]
    float* maskp = out + (size_t)NVOX * H;       // [NV]
    float* ybuf  = maskp + NVOX;                 // [E]  (p until k_out)
    float* yhard = ybuf + NEDGE;                 // [E]  (scratch until k_out)
    float* xp      = yhard;                      // 65536 floats
    float* partial = yhard + 65536;              // NBLK floats (<= 1563)
    h16*   WvThi   = (h16*)(yhard + 67104);      // 16384 h16, 16B-aligned
    h16*   WvTlo   = WvThi + 16384;
    h16*   Wm1T    = WvThi + 32768;
    float* invS    = (float*)d_ws;               // 4 bytes

    k_pre<<<NP + 128, 256, 0, stream>>>(x, Wp, bp, Wv, Wm1, xp, WvThi, WvTlo, Wm1T);
    k_main<<<NBLK, 256, 0, stream>>>(v, bv, bm1, Wm2, bm2, WvThi, WvTlo, Wm1T,
                                     xp, cei, th, gum, maskp, ybuf, partial);
    k_reduce<<<1, 256, 0, stream>>>(partial, invS);
    k_out<<<(NVOX + 31) / 32, 256, 0, stream>>>(v, x, cei, maskp, invS, vout, ybuf, yhard);
}